// Round 9
// baseline (155.652 us; speedup 1.0000x reference)
//
#include <hip/hip_runtime.h>
#include <hip/hip_bf16.h>

// Forbid FMA contraction in ALL device code below: the kNN ranking must
// bit-match the reference's uncontracted fp32 expression
//   pd[i,j] = 2*inner(i,j) - xx[i] - xx[j]
// (round 4/6/8 passed uncontracted; round 5 regressed when the compiler fused
// 2*inner-xxi into v_fma_f32). Explicit fmaf() in linear_kernel is unaffected.
#pragma clang fp contract(off)

// B=4, N=4096, C=128, K=32. All fp32. top-K LARGEST pd, tie -> lowest index.
// Round 9: hot loop slimmed — precomputed (x,y,z,xx) float4 AoS (1 dwordx4
// load + 8 fp per candidate instead of 3 scalar loads + 13 fp), exact key
// materialized only for bin-D tie candidates. Selection machinery identical
// to the proven round-8 kernel (3073-bin skewed histogram, clamped suffix
// scan, bitonic tie refinement on exact fp32 keys).

constexpr int NB   = 4;
constexpr int NP   = 4096;
constexpr int NC   = 128;
constexpr int NK   = 32;
constexpr int NT   = 256;
constexpr int PERT = NP / NT; // 16

__device__ __forceinline__ unsigned skew(unsigned d) { return d + (d >> 5); }

// ---------------------------------------------------------------------------
// Kernel P: pack pts4[b*NP+j] = (x, y, z, xx_j) with xx_j bit-identical to
// the reference's xx (uncontracted (x*x + y*y) + z*z).
// ---------------------------------------------------------------------------
__global__ __launch_bounds__(NT) void precompute_kernel(
    const float* __restrict__ xyz,    // [B,3,N]
    float4* __restrict__ pts)         // [B*NP]
{
    const int g = blockIdx.x * NT + threadIdx.x;   // 0 .. B*NP-1
    const int b = g >> 12;
    const int j = g & (NP - 1);
    const float* xb = xyz + (size_t)b * 3 * NP;
    const float x = xb[j];
    const float y = xb[NP + j];
    const float z = xb[2 * NP + j];
    const float xx = (x * x + y * y) + z * z;      // each op rounded (no FMA)
    pts[g] = make_float4(x, y, z, xx);
}

// ---------------------------------------------------------------------------
// Kernel A: per-query kNN (histogram select) + mean pool -> fp32 rows in d_out
// ---------------------------------------------------------------------------
template <bool USE_WS>
__global__ __launch_bounds__(NT) void knn_pool_kernel(
    const float*  __restrict__ xyz,    // [B,3,N]
    const float4* __restrict__ pts,    // [B*NP] (USE_WS only)
    const float*  __restrict__ feats,  // [B,N,C]
    float* __restrict__ pooled)        // [B*N, C] (d_out, fp32 temp)
{
    const int bi   = blockIdx.x;
    const int b    = bi >> 12;
    const int i    = bi & (NP - 1);
    const int t    = threadIdx.x;
    const int lane = t & 63;
    const int wid  = t >> 6;

    const float* xb = xyz + (size_t)b * 3 * NP;
    float qx, qy, qz, xxi;
    if constexpr (USE_WS) {
        const float4 qq = pts[(b << 12) | i];
        qx = qq.x; qy = qq.y; qz = qq.z; xxi = qq.w;
    } else {
        qx = xb[i]; qy = xb[NP + i]; qz = xb[2 * NP + i];
        xxi = (qx * qx + qy * qy) + qz * qz;
    }

    // pd (exact reference fp32 bits) + uniformized bin (monotone in pd)
    float    pdv[PERT];
    unsigned dg[PERT];
    #pragma unroll
    for (int m = 0; m < PERT; ++m) {
        const int j = m * NT + t;
        float px, py, pz, xxj;
        if constexpr (USE_WS) {
            const float4 p4 = pts[(b << 12) | j];
            px = p4.x; py = p4.y; pz = p4.z; xxj = p4.w;
        } else {
            px = xb[j]; py = xb[NP + j]; pz = xb[2 * NP + j];
            xxj = (px * px + py * py) + pz * pz;
        }
        const float inner = (qx * px + qy * py) + qz * pz;
        const float pd    = (2.0f * inner - xxi) - xxj;
        pdv[m] = pd;
        const float q = fmaxf(pd + 24.0f, 0.0f) * 67108864.0f;  // *2^26, exact
        dg[m] = ((unsigned)q) >> 19;                             // 0..3072
    }

    __shared__ unsigned s_hist[3200];   // 3073 skewed bins (12.8 KiB)
    __shared__ int      s_sel[NK];
    __shared__ int      s_tiej[128];
    __shared__ unsigned s_tiek[128];
    __shared__ unsigned s_G[NT];
    __shared__ unsigned s_wtot[4];
    __shared__ unsigned s_cnt, s_tiecnt, s_digit, s_kth;
    __shared__ float    s_red[NT];

    if (t == 0) { s_cnt = 0; s_tiecnt = 0; s_digit = 0; s_kth = NK; }
    if (t < NK) s_sel[t] = 0;           // defensive: never leave garbage
    for (int z = t; z < 3200; z += NT) s_hist[z] = 0u;
    __syncthreads();

    // -- histogram (spread bins => ~conflict-free LDS atomics) --
    #pragma unroll
    for (int m = 0; m < PERT; ++m)
        atomicAdd(&s_hist[skew(dg[m])], 1u);
    __syncthreads();

    // -- block suffix scan: G[t] = # keys with digit >= 16*t --
    unsigned h[16];
    unsigned hsum = 0;
    #pragma unroll
    for (int e = 0; e < 16; ++e) {
        const unsigned bin = (unsigned)(t * 16 + e);
        h[e] = (bin <= 3072u) ? s_hist[skew(bin)] : 0u;   // clamp (r7 lesson)
        hsum += h[e];
    }
    unsigned v = hsum;
    #pragma unroll
    for (int off = 1; off < 64; off <<= 1) {
        const unsigned o = __shfl_down(v, off, 64);
        if (lane + off < 64) v += o;
    }
    if (lane == 0) s_wtot[wid] = v;
    __syncthreads();
    unsigned G = v;
    for (int w = wid + 1; w < 4; ++w) G += s_wtot[w];
    s_G[t] = G;
    __syncthreads();
    const unsigned Gn = (t < NT - 1) ? s_G[t + 1] : 0u;

    // unique thread whose 16-bin chunk contains the crossing
    if (G >= (unsigned)NK && Gn < (unsigned)NK) {
        unsigned above = Gn;
        #pragma unroll
        for (int e = 15; e >= 0; --e) {
            if (above + h[e] >= (unsigned)NK) {
                s_digit = (unsigned)(t * 16 + e);
                s_kth   = (unsigned)NK - above;
                break;
            }
            above += h[e];
        }
    }
    __syncthreads();

    const unsigned D     = s_digit;
    const int      kthf0 = (int)s_kth;       // 1..32 slots from bin D
    const int      cgt   = NK - kthf0;       // # keys with digit > D (exact)

    // -- gather: digit > D -> selected; digit == D -> tie candidates
    //    (exact sign-flipped key materialized lazily, only for ties) --
    #pragma unroll
    for (int m = 0; m < PERT; ++m) {
        const int j = m * NT + t;
        if (dg[m] > D) {
            const unsigned p = atomicAdd(&s_cnt, 1u);
            if (p < (unsigned)NK) s_sel[p] = j;           // bound guard
        } else if (dg[m] == D) {
            const unsigned p = atomicAdd(&s_tiecnt, 1u);
            if (p < 128u) {
                const unsigned u = __float_as_uint(pdv[m]);
                s_tiej[p] = j;
                s_tiek[p] = (u & 0x80000000u) ? ~u : (u | 0x80000000u);
            }
        }
    }
    __syncthreads();

    const int tc   = (int)min(s_tiecnt, 128u);
    const int kthf = min(kthf0, tc);

    // -- exact refinement among bin-D candidates by (key desc, idx asc) --
    if (wid == 0) {
        if (tc <= 64) {
            // 64-lane bitonic sort, descending; lane r ends with r-th largest
            unsigned long long comp = 0ull;
            if (lane < tc)
                comp = ((unsigned long long)s_tiek[lane] << 32) |
                       (unsigned)(~(unsigned)s_tiej[lane]);
            #pragma unroll
            for (int k = 2; k <= 64; k <<= 1) {
                #pragma unroll
                for (int jj = k >> 1; jj >= 1; jj >>= 1) {
                    const unsigned long long other = __shfl_xor(comp, jj, 64);
                    const bool dirDesc = ((lane & k) == 0);
                    const bool isLow   = ((lane & jj) == 0);
                    const bool wantMax = (dirDesc == isLow);
                    const bool otherBigger = other > comp;
                    comp = (wantMax == otherBigger) ? other : comp;
                }
            }
            if (lane < kthf && cgt + lane < NK)
                s_sel[cgt + lane] = (int)(~(unsigned)(comp & 0xffffffffull));
        } else {
            // rare path (64 < tc <= 128): iterative wave-argmax extraction
            unsigned long long c0 = 0ull, c1 = 0ull;
            if (lane < tc)
                c0 = ((unsigned long long)s_tiek[lane] << 32) |
                     (unsigned)(~(unsigned)s_tiej[lane]);
            if (lane + 64 < tc)
                c1 = ((unsigned long long)s_tiek[lane + 64] << 32) |
                     (unsigned)(~(unsigned)s_tiej[lane + 64]);
            for (int r = 0; r < kthf; ++r) {
                unsigned long long w = (c0 > c1) ? c0 : c1;
                #pragma unroll
                for (int off = 32; off >= 1; off >>= 1) {
                    const unsigned long long o = __shfl_xor(w, off, 64);
                    if (o > w) w = o;
                }
                if (c0 == w) c0 = 0ull; else if (c1 == w) c1 = 0ull;
                if (lane == 0 && cgt + r < NK)
                    s_sel[cgt + r] = (int)(~(unsigned)(w & 0xffffffffull));
            }
        }
    }
    __syncthreads();

    // -- mean-pool the 32 selected rows (order-invariant) --
    const int c    = t & (NC - 1);
    const int half = t >> 7;
    const float* fb = feats + (size_t)b * NP * NC;
    float sum = 0.f;
    #pragma unroll
    for (int k = 0; k < NK / 2; ++k) {
        const int j = s_sel[half * (NK / 2) + k] & (NP - 1);  // fault-proof mask
        sum += fb[(size_t)j * NC + c];
    }
    s_red[t] = sum;
    __syncthreads();
    if (t < NC) {
        const float p = (s_red[t] + s_red[t + NC]) * (1.0f / (float)NK);
        pooled[(size_t)bi * NC + t] = p;
    }
}

// ---------------------------------------------------------------------------
// Kernel B: in-place Linear on d_out rows: io[row,d] = sum_c io[row,c]*W[d,c]
// ---------------------------------------------------------------------------
__global__ __launch_bounds__(NT) void linear_kernel(
    float* __restrict__ io,           // [B*N, C] fp32, in-place
    const float* __restrict__ W)      // [C, C] row-major W[d][c]
{
    const int t    = threadIdx.x;
    const int row0 = blockIdx.x * 64;

    __shared__ float P[64 * NC];  // 32 KiB

    const float* src = io + (size_t)row0 * NC;
    #pragma unroll
    for (int m = 0; m < 8; ++m) {
        const int e4 = m * NT + t;
        *(float4*)&P[e4 * 4] = *(const float4*)&src[e4 * 4];
    }
    __syncthreads();

    const int d     = t & (NC - 1);
    const int rbase = (t >> 7) * 32;

    float acc[32];
    #pragma unroll
    for (int k = 0; k < 32; ++k) acc[k] = 0.f;

    const float* Wd = W + (size_t)d * NC;
    for (int c4 = 0; c4 < NC / 4; ++c4) {
        const float4 w = *(const float4*)(Wd + c4 * 4);
        #pragma unroll
        for (int k = 0; k < 32; ++k) {
            const float4 pv = *(const float4*)&P[(rbase + k) * NC + c4 * 4];
            acc[k] = fmaf(pv.x, w.x, acc[k]);
            acc[k] = fmaf(pv.y, w.y, acc[k]);
            acc[k] = fmaf(pv.z, w.z, acc[k]);
            acc[k] = fmaf(pv.w, w.w, acc[k]);
        }
    }

    #pragma unroll
    for (int k = 0; k < 32; ++k) {
        io[(size_t)(row0 + rbase + k) * NC + d] = acc[k];
    }
}

// ---------------------------------------------------------------------------
extern "C" void kernel_launch(void* const* d_in, const int* in_sizes, int n_in,
                              void* d_out, int out_size, void* d_ws, size_t ws_size,
                              hipStream_t stream) {
    const float* xyz   = nullptr;  // 49152
    const float* feats = nullptr;  // 2097152
    const float* W     = nullptr;  // 16384
    for (int k = 0; k < n_in; ++k) {
        if      (in_sizes[k] == NB * 3 * NP)       xyz   = (const float*)d_in[k];
        else if (in_sizes[k] == NB * NP * NC)      feats = (const float*)d_in[k];
        else if (in_sizes[k] == NC * NC)           W     = (const float*)d_in[k];
    }
    float* out = (float*)d_out;

    if (ws_size >= sizeof(float4) * (size_t)(NB * NP)) {
        float4* pts = (float4*)d_ws;
        precompute_kernel<<<NB * NP / NT, NT, 0, stream>>>(xyz, pts);
        knn_pool_kernel<true><<<NB * NP, NT, 0, stream>>>(xyz, pts, feats, out);
    } else {
        knn_pool_kernel<false><<<NB * NP, NT, 0, stream>>>(xyz, nullptr, feats, out);
    }
    linear_kernel<<<NB * NP / 64, NT, 0, stream>>>(out, W);
}

// Round 10
// 128.062 us; speedup vs baseline: 1.2154x; 1.2154x over previous
//
#include <hip/hip_runtime.h>
#include <hip/hip_bf16.h>

// Forbid FMA contraction in ALL device code below: the kNN ranking must
// bit-match the reference's uncontracted fp32 expression
//   pd[i,j] = 2*inner(i,j) - xx[i] - xx[j]
// (round 4/6/8 passed uncontracted; round 5 regressed when the compiler fused
// 2*inner-xxi into v_fma_f32). Explicit fmaf() in linear_kernel is unaffected.
#pragma clang fp contract(off)

// B=4, N=4096, C=128, K=32. All fp32. top-K LARGEST pd, tie -> lowest index.
// Round 10: r8 structure (scalar coord loads, 44 VGPR, 51% occ — r9's float4
// AoS dropped occupancy to 42% and regressed) + two VALU-only cuts:
//   (a) xxj loaded as a 4B scalar from precomputed ws (replaces 5 VALU ops;
//       bit-identical pd since the stored bits are the same uncontracted xx),
//   (b) lazy exact-key: keep pd in regs, materialize sign-flipped key only
//       for bin-D tie candidates (r9's proven change).
// Selection machinery identical to round 8.

constexpr int NB   = 4;
constexpr int NP   = 4096;
constexpr int NC   = 128;
constexpr int NK   = 32;
constexpr int NT   = 256;
constexpr int PERT = NP / NT; // 16

__device__ __forceinline__ unsigned skew(unsigned d) { return d + (d >> 5); }

// ---------------------------------------------------------------------------
// Kernel P: xxw[b*NP+j] = xx_j, bit-identical to the reference's
// uncontracted (x*x + y*y) + z*z.
// ---------------------------------------------------------------------------
__global__ __launch_bounds__(NT) void precompute_kernel(
    const float* __restrict__ xyz,    // [B,3,N]
    float* __restrict__ xxw)          // [B*NP]
{
    const int g = blockIdx.x * NT + threadIdx.x;   // 0 .. B*NP-1
    const int b = g >> 12;
    const int j = g & (NP - 1);
    const float* xb = xyz + (size_t)b * 3 * NP;
    const float x = xb[j];
    const float y = xb[NP + j];
    const float z = xb[2 * NP + j];
    xxw[g] = (x * x + y * y) + z * z;              // each op rounded (no FMA)
}

// ---------------------------------------------------------------------------
// Kernel A: per-query kNN (histogram select) + mean pool -> fp32 rows in d_out
// ---------------------------------------------------------------------------
template <bool USE_WS>
__global__ __launch_bounds__(NT) void knn_pool_kernel(
    const float* __restrict__ xyz,    // [B,3,N]
    const float* __restrict__ xxw,    // [B*NP] (USE_WS only)
    const float* __restrict__ feats,  // [B,N,C]
    float* __restrict__ pooled)       // [B*N, C] (d_out, fp32 temp)
{
    const int bi   = blockIdx.x;
    const int b    = bi >> 12;
    const int i    = bi & (NP - 1);
    const int t    = threadIdx.x;
    const int lane = t & 63;
    const int wid  = t >> 6;

    const float* xb  = xyz + (size_t)b * 3 * NP;
    const float* xxb = USE_WS ? (xxw + ((size_t)b << 12)) : nullptr;

    const float qx = xb[i];
    const float qy = xb[NP + i];
    const float qz = xb[2 * NP + i];
    float xxi;
    if constexpr (USE_WS) xxi = xxb[i];
    else                  xxi = (qx * qx + qy * qy) + qz * qz;

    // pd (exact reference fp32 bits) + uniformized bin (monotone in pd)
    float    pdv[PERT];
    unsigned dg[PERT];
    #pragma unroll
    for (int m = 0; m < PERT; ++m) {
        const int j = m * NT + t;
        const float px = xb[j];
        const float py = xb[NP + j];
        const float pz = xb[2 * NP + j];
        float xxj;
        if constexpr (USE_WS) xxj = xxb[j];     // 4B scalar, L1-resident
        else                  xxj = (px * px + py * py) + pz * pz;
        const float inner = (qx * px + qy * py) + qz * pz;
        const float pd    = (2.0f * inner - xxi) - xxj;
        pdv[m] = pd;
        const float q = fmaxf(pd + 24.0f, 0.0f) * 67108864.0f;  // *2^26, exact
        dg[m] = ((unsigned)q) >> 19;                             // 0..3072
    }

    __shared__ unsigned s_hist[3200];   // 3073 skewed bins (12.8 KiB)
    __shared__ int      s_sel[NK];
    __shared__ int      s_tiej[128];
    __shared__ unsigned s_tiek[128];
    __shared__ unsigned s_G[NT];
    __shared__ unsigned s_wtot[4];
    __shared__ unsigned s_cnt, s_tiecnt, s_digit, s_kth;
    __shared__ float    s_red[NT];

    if (t == 0) { s_cnt = 0; s_tiecnt = 0; s_digit = 0; s_kth = NK; }
    if (t < NK) s_sel[t] = 0;           // defensive: never leave garbage
    for (int z = t; z < 3200; z += NT) s_hist[z] = 0u;
    __syncthreads();

    // -- histogram (spread bins => ~conflict-free LDS atomics) --
    #pragma unroll
    for (int m = 0; m < PERT; ++m)
        atomicAdd(&s_hist[skew(dg[m])], 1u);
    __syncthreads();

    // -- block suffix scan: G[t] = # keys with digit >= 16*t --
    unsigned h[16];
    unsigned hsum = 0;
    #pragma unroll
    for (int e = 0; e < 16; ++e) {
        const unsigned bin = (unsigned)(t * 16 + e);
        h[e] = (bin <= 3072u) ? s_hist[skew(bin)] : 0u;   // clamp (r7 lesson)
        hsum += h[e];
    }
    unsigned v = hsum;
    #pragma unroll
    for (int off = 1; off < 64; off <<= 1) {
        const unsigned o = __shfl_down(v, off, 64);
        if (lane + off < 64) v += o;
    }
    if (lane == 0) s_wtot[wid] = v;
    __syncthreads();
    unsigned G = v;
    for (int w = wid + 1; w < 4; ++w) G += s_wtot[w];
    s_G[t] = G;
    __syncthreads();
    const unsigned Gn = (t < NT - 1) ? s_G[t + 1] : 0u;

    // unique thread whose 16-bin chunk contains the crossing
    if (G >= (unsigned)NK && Gn < (unsigned)NK) {
        unsigned above = Gn;
        #pragma unroll
        for (int e = 15; e >= 0; --e) {
            if (above + h[e] >= (unsigned)NK) {
                s_digit = (unsigned)(t * 16 + e);
                s_kth   = (unsigned)NK - above;
                break;
            }
            above += h[e];
        }
    }
    __syncthreads();

    const unsigned D     = s_digit;
    const int      kthf0 = (int)s_kth;       // 1..32 slots from bin D
    const int      cgt   = NK - kthf0;       // # keys with digit > D (exact)

    // -- gather: digit > D -> selected; digit == D -> tie candidates
    //    (exact sign-flipped key materialized lazily, only for ties) --
    #pragma unroll
    for (int m = 0; m < PERT; ++m) {
        const int j = m * NT + t;
        if (dg[m] > D) {
            const unsigned p = atomicAdd(&s_cnt, 1u);
            if (p < (unsigned)NK) s_sel[p] = j;           // bound guard
        } else if (dg[m] == D) {
            const unsigned p = atomicAdd(&s_tiecnt, 1u);
            if (p < 128u) {
                const unsigned u = __float_as_uint(pdv[m]);
                s_tiej[p] = j;
                s_tiek[p] = (u & 0x80000000u) ? ~u : (u | 0x80000000u);
            }
        }
    }
    __syncthreads();

    const int tc   = (int)min(s_tiecnt, 128u);
    const int kthf = min(kthf0, tc);

    // -- exact refinement among bin-D candidates by (key desc, idx asc) --
    if (wid == 0) {
        if (tc <= 64) {
            // 64-lane bitonic sort, descending; lane r ends with r-th largest
            unsigned long long comp = 0ull;
            if (lane < tc)
                comp = ((unsigned long long)s_tiek[lane] << 32) |
                       (unsigned)(~(unsigned)s_tiej[lane]);
            #pragma unroll
            for (int k = 2; k <= 64; k <<= 1) {
                #pragma unroll
                for (int jj = k >> 1; jj >= 1; jj >>= 1) {
                    const unsigned long long other = __shfl_xor(comp, jj, 64);
                    const bool dirDesc = ((lane & k) == 0);
                    const bool isLow   = ((lane & jj) == 0);
                    const bool wantMax = (dirDesc == isLow);
                    const bool otherBigger = other > comp;
                    comp = (wantMax == otherBigger) ? other : comp;
                }
            }
            if (lane < kthf && cgt + lane < NK)
                s_sel[cgt + lane] = (int)(~(unsigned)(comp & 0xffffffffull));
        } else {
            // rare path (64 < tc <= 128): iterative wave-argmax extraction
            unsigned long long c0 = 0ull, c1 = 0ull;
            if (lane < tc)
                c0 = ((unsigned long long)s_tiek[lane] << 32) |
                     (unsigned)(~(unsigned)s_tiej[lane]);
            if (lane + 64 < tc)
                c1 = ((unsigned long long)s_tiek[lane + 64] << 32) |
                     (unsigned)(~(unsigned)s_tiej[lane + 64]);
            for (int r = 0; r < kthf; ++r) {
                unsigned long long w = (c0 > c1) ? c0 : c1;
                #pragma unroll
                for (int off = 32; off >= 1; off >>= 1) {
                    const unsigned long long o = __shfl_xor(w, off, 64);
                    if (o > w) w = o;
                }
                if (c0 == w) c0 = 0ull; else if (c1 == w) c1 = 0ull;
                if (lane == 0 && cgt + r < NK)
                    s_sel[cgt + r] = (int)(~(unsigned)(w & 0xffffffffull));
            }
        }
    }
    __syncthreads();

    // -- mean-pool the 32 selected rows (order-invariant) --
    const int c    = t & (NC - 1);
    const int half = t >> 7;
    const float* fb = feats + (size_t)b * NP * NC;
    float sum = 0.f;
    #pragma unroll
    for (int k = 0; k < NK / 2; ++k) {
        const int j = s_sel[half * (NK / 2) + k] & (NP - 1);  // fault-proof mask
        sum += fb[(size_t)j * NC + c];
    }
    s_red[t] = sum;
    __syncthreads();
    if (t < NC) {
        const float p = (s_red[t] + s_red[t + NC]) * (1.0f / (float)NK);
        pooled[(size_t)bi * NC + t] = p;
    }
}

// ---------------------------------------------------------------------------
// Kernel B: in-place Linear on d_out rows: io[row,d] = sum_c io[row,c]*W[d,c]
// ---------------------------------------------------------------------------
__global__ __launch_bounds__(NT) void linear_kernel(
    float* __restrict__ io,           // [B*N, C] fp32, in-place
    const float* __restrict__ W)      // [C, C] row-major W[d][c]
{
    const int t    = threadIdx.x;
    const int row0 = blockIdx.x * 64;

    __shared__ float P[64 * NC];  // 32 KiB

    const float* src = io + (size_t)row0 * NC;
    #pragma unroll
    for (int m = 0; m < 8; ++m) {
        const int e4 = m * NT + t;
        *(float4*)&P[e4 * 4] = *(const float4*)&src[e4 * 4];
    }
    __syncthreads();

    const int d     = t & (NC - 1);
    const int rbase = (t >> 7) * 32;

    float acc[32];
    #pragma unroll
    for (int k = 0; k < 32; ++k) acc[k] = 0.f;

    const float* Wd = W + (size_t)d * NC;
    for (int c4 = 0; c4 < NC / 4; ++c4) {
        const float4 w = *(const float4*)(Wd + c4 * 4);
        #pragma unroll
        for (int k = 0; k < 32; ++k) {
            const float4 pv = *(const float4*)&P[(rbase + k) * NC + c4 * 4];
            acc[k] = fmaf(pv.x, w.x, acc[k]);
            acc[k] = fmaf(pv.y, w.y, acc[k]);
            acc[k] = fmaf(pv.z, w.z, acc[k]);
            acc[k] = fmaf(pv.w, w.w, acc[k]);
        }
    }

    #pragma unroll
    for (int k = 0; k < 32; ++k) {
        io[(size_t)(row0 + rbase + k) * NC + d] = acc[k];
    }
}

// ---------------------------------------------------------------------------
extern "C" void kernel_launch(void* const* d_in, const int* in_sizes, int n_in,
                              void* d_out, int out_size, void* d_ws, size_t ws_size,
                              hipStream_t stream) {
    const float* xyz   = nullptr;  // 49152
    const float* feats = nullptr;  // 2097152
    const float* W     = nullptr;  // 16384
    for (int k = 0; k < n_in; ++k) {
        if      (in_sizes[k] == NB * 3 * NP)       xyz   = (const float*)d_in[k];
        else if (in_sizes[k] == NB * NP * NC)      feats = (const float*)d_in[k];
        else if (in_sizes[k] == NC * NC)           W     = (const float*)d_in[k];
    }
    float* out = (float*)d_out;

    if (ws_size >= sizeof(float) * (size_t)(NB * NP)) {
        float* xxw = (float*)d_ws;
        precompute_kernel<<<NB * NP / NT, NT, 0, stream>>>(xyz, xxw);
        knn_pool_kernel<true><<<NB * NP, NT, 0, stream>>>(xyz, xxw, feats, out);
    } else {
        knn_pool_kernel<false><<<NB * NP, NT, 0, stream>>>(xyz, nullptr, feats, out);
    }
    linear_kernel<<<NB * NP / 64, NT, 0, stream>>>(out, W);
}

// Round 11
// 125.864 us; speedup vs baseline: 1.2367x; 1.0175x over previous
//
#include <hip/hip_runtime.h>
#include <hip/hip_bf16.h>

// Forbid FMA contraction in ALL device code below: the kNN ranking must
// bit-match the reference's uncontracted fp32 expression
//   pd[i,j] = 2*inner(i,j) - xx[i] - xx[j]
// (rounds 4/6/8/10 passed uncontracted; round 5 regressed when the compiler
// fused 2*inner-xxi into v_fma_f32). fmaf() in linear_kernel is unaffected.
#pragma clang fp contract(off)

// B=4, N=4096, C=128, K=32. All fp32. top-K LARGEST pd, tie -> lowest index.
// Round 11: threshold-prefilter selection.
//   - 32nd-largest of the 256 per-thread maxima <= true 32nd-largest (subset
//     order-statistic property) -> safe threshold.
//   - histogram 256 maxima (1 atomic/thread, was 16), reuse r10's suffix scan
//     to find its crossing bin D; conservative exact-float bin edge.
//   - survivors (pd >= edge, E[~38]) refined exactly by (ky desc, idx asc)
//     via the proven 64-lane bitonic; mid path 65..256 via 4/lane extraction.
// Cuts main-loop VALU ~40% (no per-candidate bin, no dg[16]) AND LDS ops ~40%.

constexpr int NB   = 4;
constexpr int NP   = 4096;
constexpr int NC   = 128;
constexpr int NK   = 32;
constexpr int NT   = 256;
constexpr int PERT = NP / NT; // 16

__device__ __forceinline__ unsigned skew(unsigned d) { return d + (d >> 5); }

// ---------------------------------------------------------------------------
// Kernel P: xxw[b*NP+j] = xx_j, bit-identical to the reference's
// uncontracted (x*x + y*y) + z*z.
// ---------------------------------------------------------------------------
__global__ __launch_bounds__(NT) void precompute_kernel(
    const float* __restrict__ xyz,    // [B,3,N]
    float* __restrict__ xxw)          // [B*NP]
{
    const int g = blockIdx.x * NT + threadIdx.x;   // 0 .. B*NP-1
    const int b = g >> 12;
    const int j = g & (NP - 1);
    const float* xb = xyz + (size_t)b * 3 * NP;
    const float x = xb[j];
    const float y = xb[NP + j];
    const float z = xb[2 * NP + j];
    xxw[g] = (x * x + y * y) + z * z;              // each op rounded (no FMA)
}

// ---------------------------------------------------------------------------
// Kernel A: per-query kNN (prefilter select) + mean pool -> fp32 rows in d_out
// ---------------------------------------------------------------------------
template <bool USE_WS>
__global__ __launch_bounds__(NT) void knn_pool_kernel(
    const float* __restrict__ xyz,    // [B,3,N]
    const float* __restrict__ xxw,    // [B*NP] (USE_WS only)
    const float* __restrict__ feats,  // [B,N,C]
    float* __restrict__ pooled)       // [B*N, C] (d_out, fp32 temp)
{
    const int bi   = blockIdx.x;
    const int b    = bi >> 12;
    const int i    = bi & (NP - 1);
    const int t    = threadIdx.x;
    const int lane = t & 63;
    const int wid  = t >> 6;

    const float* xb  = xyz + (size_t)b * 3 * NP;
    const float* xxb = USE_WS ? (xxw + ((size_t)b << 12)) : nullptr;

    const float qx = xb[i];
    const float qy = xb[NP + i];
    const float qz = xb[2 * NP + i];
    float xxi;
    if constexpr (USE_WS) xxi = xxb[i];
    else                  xxi = (qx * qx + qy * qy) + qz * qz;

    // pd (exact reference fp32 bits) + running thread-max
    float pdv[PERT];
    float tmax = -3.0e38f;
    #pragma unroll
    for (int m = 0; m < PERT; ++m) {
        const int j = m * NT + t;
        const float px = xb[j];
        const float py = xb[NP + j];
        const float pz = xb[2 * NP + j];
        float xxj;
        if constexpr (USE_WS) xxj = xxb[j];     // 4B scalar, L1-resident
        else                  xxj = (px * px + py * py) + pz * pz;
        const float inner = (qx * px + qy * py) + qz * pz;
        const float pd    = (2.0f * inner - xxi) - xxj;
        pdv[m] = pd;
        tmax = fmaxf(tmax, pd);
    }
    // bin of the thread max (monotone map, same as r6-r10's uniformized bin)
    const float qmax = fmaxf(tmax + 24.0f, 0.0f) * 67108864.0f;  // *2^26, exact
    const unsigned dgmax = min(((unsigned)qmax) >> 19, 3072u);    // 0..3072

    __shared__ unsigned s_hist[3200];   // 3073 skewed bins (12.8 KiB)
    __shared__ int      s_sel[NK];
    __shared__ int      s_sj[256];
    __shared__ unsigned s_sk[256];
    __shared__ unsigned s_G[NT];
    __shared__ unsigned s_wtot[4];
    __shared__ unsigned s_scnt, s_digit;
    __shared__ float    s_red[NT];

    if (t == 0) { s_scnt = 0; s_digit = 0; }
    if (t < NK) s_sel[t] = 0;           // defensive: never leave garbage
    {   // wide zeroing: 800 uint4 across 256 threads
        uint4* hz = (uint4*)s_hist;
        for (int z = t; z < 800; z += NT) hz[z] = make_uint4(0u, 0u, 0u, 0u);
    }
    __syncthreads();

    // -- histogram of the 256 thread-maxima (1 atomic per thread) --
    atomicAdd(&s_hist[skew(dgmax)], 1u);
    __syncthreads();

    // -- block suffix scan (verbatim r10): G[t] = # maxima with bin >= 16*t --
    unsigned h[16];
    unsigned hsum = 0;
    #pragma unroll
    for (int e = 0; e < 16; ++e) {
        const unsigned bin = (unsigned)(t * 16 + e);
        h[e] = (bin <= 3072u) ? s_hist[skew(bin)] : 0u;   // clamp (r7 lesson)
        hsum += h[e];
    }
    unsigned v = hsum;
    #pragma unroll
    for (int off = 1; off < 64; off <<= 1) {
        const unsigned o = __shfl_down(v, off, 64);
        if (lane + off < 64) v += o;
    }
    if (lane == 0) s_wtot[wid] = v;
    __syncthreads();
    unsigned G = v;
    for (int w = wid + 1; w < 4; ++w) G += s_wtot[w];
    s_G[t] = G;
    __syncthreads();
    const unsigned Gn = (t < NT - 1) ? s_G[t + 1] : 0u;

    // unique thread whose 16-bin chunk contains the crossing at rank NK
    if (G >= (unsigned)NK && Gn < (unsigned)NK) {
        unsigned above = Gn;
        #pragma unroll
        for (int e = 15; e >= 0; --e) {
            if (above + h[e] >= (unsigned)NK) {
                s_digit = (unsigned)(t * 16 + e);
                break;
            }
            above += h[e];
        }
    }
    __syncthreads();

    // Conservative float edge of bin D: D*2^-7 - 24 - 2^-18 (each op exact).
    // Guarantees: bin(pd) >= D  =>  pd >= edge; and edge <= 32nd thread-max
    // <= true v32  => all top-32 survive. >=32 threads' maxima survive, so
    // survivor count sc >= 32 always.
    const unsigned D = s_digit;
    const float edge = ((float)D * 0.0078125f - 24.0f) - 0x1p-18f;

    // -- survivor pass: pd >= edge -> (index, exact sign-flipped key) --
    #pragma unroll
    for (int m = 0; m < PERT; ++m) {
        if (pdv[m] >= edge) {
            const unsigned p = atomicAdd(&s_scnt, 1u);
            if (p < 256u) {
                const unsigned u = __float_as_uint(pdv[m]);
                s_sj[p] = m * NT + t;
                s_sk[p] = (u & 0x80000000u) ? ~u : (u | 0x80000000u);
            }
        }
    }
    __syncthreads();

    const int sc = (int)min(s_scnt, 256u);

    // -- exact top-32 among survivors by (key desc, idx asc) --
    if (wid == 0) {
        if (sc <= 64) {
            // proven 64-lane bitonic, descending; lanes 0..31 = top-32
            unsigned long long comp = 0ull;   // padding sorts below all real
            if (lane < sc)
                comp = ((unsigned long long)s_sk[lane] << 32) |
                       (unsigned)(~(unsigned)s_sj[lane]);
            #pragma unroll
            for (int k = 2; k <= 64; k <<= 1) {
                #pragma unroll
                for (int jj = k >> 1; jj >= 1; jj >>= 1) {
                    const unsigned long long other = __shfl_xor(comp, jj, 64);
                    const bool dirDesc = ((lane & k) == 0);
                    const bool isLow   = ((lane & jj) == 0);
                    const bool wantMax = (dirDesc == isLow);
                    const bool otherBigger = other > comp;
                    comp = (wantMax == otherBigger) ? other : comp;
                }
            }
            if (lane < NK)
                s_sel[lane] = (int)(~(unsigned)(comp & 0xffffffffull));
        } else {
            // rare path (65..256 survivors): 4 composites/lane, 32 rounds of
            // wave-argmax extraction (composites unique; butterfly leaves the
            // global max in all lanes).
            unsigned long long c[4];
            #pragma unroll
            for (int q = 0; q < 4; ++q) {
                const int idx = lane + 64 * q;
                c[q] = (idx < sc)
                     ? (((unsigned long long)s_sk[idx] << 32) |
                        (unsigned)(~(unsigned)s_sj[idx]))
                     : 0ull;
            }
            for (int r = 0; r < NK; ++r) {
                unsigned long long w = c[0];
                #pragma unroll
                for (int q = 1; q < 4; ++q) if (c[q] > w) w = c[q];
                #pragma unroll
                for (int off = 32; off >= 1; off >>= 1) {
                    const unsigned long long o = __shfl_xor(w, off, 64);
                    if (o > w) w = o;
                }
                #pragma unroll
                for (int q = 0; q < 4; ++q) if (c[q] == w) c[q] = 0ull;
                if (lane == 0)
                    s_sel[r] = (int)(~(unsigned)(w & 0xffffffffull));
            }
        }
    }
    __syncthreads();

    // -- mean-pool the 32 selected rows (sorted order -> deterministic sum) --
    const int c    = t & (NC - 1);
    const int half = t >> 7;
    const float* fb = feats + (size_t)b * NP * NC;
    float sum = 0.f;
    #pragma unroll
    for (int k = 0; k < NK / 2; ++k) {
        const int j = s_sel[half * (NK / 2) + k] & (NP - 1);  // fault-proof mask
        sum += fb[(size_t)j * NC + c];
    }
    s_red[t] = sum;
    __syncthreads();
    if (t < NC) {
        const float p = (s_red[t] + s_red[t + NC]) * (1.0f / (float)NK);
        pooled[(size_t)bi * NC + t] = p;
    }
}

// ---------------------------------------------------------------------------
// Kernel B: in-place Linear on d_out rows: io[row,d] = sum_c io[row,c]*W[d,c]
// ---------------------------------------------------------------------------
__global__ __launch_bounds__(NT) void linear_kernel(
    float* __restrict__ io,           // [B*N, C] fp32, in-place
    const float* __restrict__ W)      // [C, C] row-major W[d][c]
{
    const int t    = threadIdx.x;
    const int row0 = blockIdx.x * 64;

    __shared__ float P[64 * NC];  // 32 KiB

    const float* src = io + (size_t)row0 * NC;
    #pragma unroll
    for (int m = 0; m < 8; ++m) {
        const int e4 = m * NT + t;
        *(float4*)&P[e4 * 4] = *(const float4*)&src[e4 * 4];
    }
    __syncthreads();

    const int d     = t & (NC - 1);
    const int rbase = (t >> 7) * 32;

    float acc[32];
    #pragma unroll
    for (int k = 0; k < 32; ++k) acc[k] = 0.f;

    const float* Wd = W + (size_t)d * NC;
    for (int c4 = 0; c4 < NC / 4; ++c4) {
        const float4 w = *(const float4*)(Wd + c4 * 4);
        #pragma unroll
        for (int k = 0; k < 32; ++k) {
            const float4 pv = *(const float4*)&P[(rbase + k) * NC + c4 * 4];
            acc[k] = fmaf(pv.x, w.x, acc[k]);
            acc[k] = fmaf(pv.y, w.y, acc[k]);
            acc[k] = fmaf(pv.z, w.z, acc[k]);
            acc[k] = fmaf(pv.w, w.w, acc[k]);
        }
    }

    #pragma unroll
    for (int k = 0; k < 32; ++k) {
        io[(size_t)(row0 + rbase + k) * NC + d] = acc[k];
    }
}

// ---------------------------------------------------------------------------
extern "C" void kernel_launch(void* const* d_in, const int* in_sizes, int n_in,
                              void* d_out, int out_size, void* d_ws, size_t ws_size,
                              hipStream_t stream) {
    const float* xyz   = nullptr;  // 49152
    const float* feats = nullptr;  // 2097152
    const float* W     = nullptr;  // 16384
    for (int k = 0; k < n_in; ++k) {
        if      (in_sizes[k] == NB * 3 * NP)       xyz   = (const float*)d_in[k];
        else if (in_sizes[k] == NB * NP * NC)      feats = (const float*)d_in[k];
        else if (in_sizes[k] == NC * NC)           W     = (const float*)d_in[k];
    }
    float* out = (float*)d_out;

    if (ws_size >= sizeof(float) * (size_t)(NB * NP)) {
        float* xxw = (float*)d_ws;
        precompute_kernel<<<NB * NP / NT, NT, 0, stream>>>(xyz, xxw);
        knn_pool_kernel<true><<<NB * NP, NT, 0, stream>>>(xyz, xxw, feats, out);
    } else {
        knn_pool_kernel<false><<<NB * NP, NT, 0, stream>>>(xyz, nullptr, feats, out);
    }
    linear_kernel<<<NB * NP / 64, NT, 0, stream>>>(out, W);
}